// Round 1
// 1042.551 us; speedup vs baseline: 1.1168x; 1.1168x over previous
//
#include <hip/hip_runtime.h>
#include <hip/hip_bf16.h>

#define B_   256
#define T_   512
#define H_   128
#define G3_  384

// ---- tiled GEMM config ----
#define TM   128
#define TN   128
#define TK   32
#define LDA  132

// dynamic-LDS clamp for gru_rec: force 1 block/CU at runtime so the declared
// __launch_bounds__(1024, 4) occupancy (4 waves/EU -> 128-VGPR budget) is
// physically achievable. NOTE (R9): the clamp ALONE does not work — dynamic
// LDS size is invisible to the register allocator (VGPR_Count stayed 40).
// The budget must come from launch_bounds' second arg.
#define REC_LDS_BYTES 102400

typedef float v4f __attribute__((ext_vector_type(4)));

__device__ __forceinline__ float sigmoid_f(float x) {
    return 1.0f / (1.0f + __expf(-x));
}
__device__ __forceinline__ float tanh_f(float x) {
    return 1.0f - 2.0f / (__expf(2.0f * x) + 1.0f);
}

// Butterfly sum over each aligned 8-lane group, pure DPP (no LDS pipe),
// result valid on ALL lanes: quad_perm xor1, quad_perm xor2, row_half_mirror.
__device__ __forceinline__ float bfly_fold8(float v) {
    int x;
    x = __builtin_amdgcn_update_dpp(0, __float_as_int(v), 0x0B1, 0xF, 0xF, true);
    v += __int_as_float(x);   // xor 1
    x = __builtin_amdgcn_update_dpp(0, __float_as_int(v), 0x04E, 0xF, 0xF, true);
    v += __int_as_float(x);   // xor 2
    x = __builtin_amdgcn_update_dpp(0, __float_as_int(v), 0x141, 0xF, 0xF, true);
    v += __int_as_float(x);   // other quad (half mirror)
    return v;
}

#define DOT4(acc, hv, wv)                                        \
    acc = fmaf((hv).x, (wv).x, acc);                             \
    acc = fmaf((hv).y, (wv).y, acc);                             \
    acc = fmaf((hv).z, (wv).z, acc);                             \
    acc = fmaf((hv).w, (wv).w, acc);

// ---------------------------------------------------------------------------
// gx GEMM (unchanged from R2 — ~150 us, healthy)
// ---------------------------------------------------------------------------
template<bool GATHER>
__global__ __launch_bounds__(256, 2)
void gx_gemm(const float* __restrict__ X,
             const int*   __restrict__ idx,
             const float* __restrict__ emb,
             const float* __restrict__ W,     // [384,128] row-major
             const float* __restrict__ bias,  // [384]
             float*       __restrict__ gx)    // [M,384]
{
    __shared__ __align__(16) float As[2][TK][LDA];
    __shared__ __align__(16) float Bs[2][TK][LDA];

    const int tid = threadIdx.x;
    const int tn  = tid & 15;
    const int tm  = tid >> 4;
    const int n0  = blockIdx.x * TN;
    const int m0  = blockIdx.y * TM;

    const int q  = tid & 7;
    const float* rowA[4];
    const float* rowB[4];
#pragma unroll
    for (int s = 0; s < 4; s++) {
        const int r = (tid >> 3) + 32 * s;
        rowA[s] = GATHER ? (emb + (size_t)idx[m0 + r] * H_)
                         : (X + (size_t)(m0 + r) * H_);
        rowB[s] = W + (size_t)(n0 + r) * H_;
    }

    float4 stA[4], stB[4];
    auto load_chunk = [&](int kc) {
#pragma unroll
        for (int s = 0; s < 4; s++) {
            stA[s] = *(const float4*)(rowA[s] + kc + q * 4);
            stB[s] = *(const float4*)(rowB[s] + kc + q * 4);
        }
    };
    auto store_chunk = [&](int buf) {
#pragma unroll
        for (int s = 0; s < 4; s++) {
            const int r = (tid >> 3) + 32 * s;
#pragma unroll
            for (int d = 0; d < 4; d++) {
                As[buf][q * 4 + d][r] = ((const float*)&stA[s])[d];
                Bs[buf][q * 4 + d][r] = ((const float*)&stB[s])[d];
            }
        }
    };

    float4 acc[2][2][4];
#pragma unroll
    for (int a = 0; a < 2; a++)
#pragma unroll
        for (int b = 0; b < 2; b++)
#pragma unroll
            for (int c = 0; c < 4; c++) acc[a][b][c] = make_float4(0.f, 0.f, 0.f, 0.f);

    load_chunk(0);
    store_chunk(0);
    __syncthreads();

    for (int c = 0; c < 4; c++) {
        if (c < 3) load_chunk((c + 1) * TK);
        const int buf = c & 1;
#pragma unroll 4
        for (int k = 0; k < TK; k++) {
            float4 a0 = *(const float4*)&As[buf][k][tm * 4];
            float4 a1 = *(const float4*)&As[buf][k][64 + tm * 4];
            float4 b0 = *(const float4*)&Bs[buf][k][tn * 4];
            float4 b1 = *(const float4*)&Bs[buf][k][64 + tn * 4];
            float4 av[2] = {a0, a1}, bv[2] = {b0, b1};
#pragma unroll
            for (int mg = 0; mg < 2; mg++)
#pragma unroll
                for (int mi = 0; mi < 4; mi++) {
                    const float am = ((const float*)&av[mg])[mi];
#pragma unroll
                    for (int ng = 0; ng < 2; ng++) {
                        acc[mg][ng][mi].x = fmaf(am, bv[ng].x, acc[mg][ng][mi].x);
                        acc[mg][ng][mi].y = fmaf(am, bv[ng].y, acc[mg][ng][mi].y);
                        acc[mg][ng][mi].z = fmaf(am, bv[ng].z, acc[mg][ng][mi].z);
                        acc[mg][ng][mi].w = fmaf(am, bv[ng].w, acc[mg][ng][mi].w);
                    }
                }
        }
        if (c < 3) {
            store_chunk(buf ^ 1);
            __syncthreads();
        }
    }

    const float4 bb0 = *(const float4*)(bias + n0 + tn * 4);
    const float4 bb1 = *(const float4*)(bias + n0 + 64 + tn * 4);
#pragma unroll
    for (int mg = 0; mg < 2; mg++)
#pragma unroll
        for (int mi = 0; mi < 4; mi++) {
            const int m = m0 + mg * 64 + tm * 4 + mi;
            float* dst = gx + (size_t)m * G3_ + n0;
            float4 v0 = acc[mg][0][mi];
            v0.x += bb0.x; v0.y += bb0.y; v0.z += bb0.z; v0.w += bb0.w;
            float4 v1 = acc[mg][1][mi];
            v1.x += bb1.x; v1.y += bb1.y; v1.z += bb1.z; v1.w += bb1.w;
            *(float4*)(dst + tn * 4) = v0;
            *(float4*)(dst + 64 + tn * 4) = v1;
        }
}

// ---------------------------------------------------------------------------
// GRU recurrence, split-K (R7 structure). One block (1024 thr) per batch row.
// Thread (jg = tid>>3, ks = tid&7): owns W_hh rows 3jg..3jg+2, cols
// ks*16..+15 = 48 floats that must stay in VGPRs.
//
// R9 change: __launch_bounds__(1024, 4) — second arg is MIN WAVES PER EU,
// so 4 waves/EU => 512/4 = 128-VGPR allocator budget. (The R8 dynamic-LDS
// clamp alone failed: the allocator can't see launch-time LDS size, kept
// targeting 8 waves/EU / 64 VGPRs, and sank W to per-step reloads —
// VGPR_Count=40, 196 KB/CU/step L1+L2 stream = 1890 cyc/step.)
// Additionally the W fragment is pinned with an empty asm so the 12 loads
// cannot be re-sunk into the T-loop. Live set ~90 VGPR < 128: no spill.
// ---------------------------------------------------------------------------
template<bool STORE_H, bool FINAL>
__global__ __launch_bounds__(1024, 4)
void gru_rec(const float* __restrict__ gx,   // [B,T,384]
             const float* __restrict__ Whh,  // [384,128]
             const float* __restrict__ bhh,  // [384]
             float*       __restrict__ hseq, // [B,T,128] if STORE_H
             const float* __restrict__ fc_w, // [3,128]  if FINAL
             const float* __restrict__ fc_b, // [3]      if FINAL
             float*       __restrict__ out)  // [B,3]    if FINAL
{
    extern __shared__ __align__(16) float smem[];
    float* h2 = smem;          // [128] swizzled h
    float* gh = smem + H_;     // [384]

    const int tid = threadIdx.x;
    const int b   = blockIdx.x;
    const int jg  = tid >> 3;      // 0..127
    const int ks  = tid & 7;       // 0..7
    const int j0  = jg * 3;

    // --- W_hh fragment: 12 float4 in named registers ---
    const v4f* w0p = (const v4f*)(Whh + (size_t)(j0    ) * H_ + ks * 16);
    const v4f* w1p = (const v4f*)(Whh + (size_t)(j0 + 1) * H_ + ks * 16);
    const v4f* w2p = (const v4f*)(Whh + (size_t)(j0 + 2) * H_ + ks * 16);
    v4f w00 = w0p[0], w01 = w0p[1], w02 = w0p[2], w03 = w0p[3];
    v4f w10 = w1p[0], w11 = w1p[1], w12 = w1p[2], w13 = w1p[3];
    v4f w20 = w2p[0], w21 = w2p[1], w22 = w2p[2], w23 = w2p[3];

    // --- gate-thread state (tid < 128) ---
    const bool gate = (tid < H_);
    float bhr = 0.f, bhz = 0.f, bhn = 0.f;
    float gr = 0.f, gz = 0.f, gn = 0.f;
    float h_old = 0.f;
    int   hw = 0;
    const float* gxb = gx + (size_t)b * T_ * G3_;
    if (gate) {
        bhr = bhh[tid]; bhz = bhh[tid + H_]; bhn = bhh[tid + 2 * H_];
        gr = gxb[tid]; gz = gxb[tid + H_]; gn = gxb[tid + 2 * H_];
        hw = ((tid >> 2) & 3) * 32 + (tid >> 4) * 4 + (tid & 3);
        h2[tid] = 0.0f;   // zeros are swizzle-invariant
    }
    __syncthreads();

    // Pin the W fragment: values become asm outputs, so the global loads
    // cannot be sunk into the loop; with the 128-VGPR budget they stay
    // register-resident for all 512 steps.
    asm volatile("" : "+v"(w00), "+v"(w01), "+v"(w02), "+v"(w03),
                      "+v"(w10), "+v"(w11), "+v"(w12), "+v"(w13),
                      "+v"(w20), "+v"(w21), "+v"(w22), "+v"(w23));

    const int hb = ks * 4;  // base word of this thread's k-slice (swizzled)

    for (int t = 0; t < T_; t++) {
        // prefetch next step's gx (covered by this step's compute)
        float gr2 = 0.f, gz2 = 0.f, gn2 = 0.f;
        if (gate) {
            const float* gnx = gxb + (size_t)min(t + 1, T_ - 1) * G3_;
            gr2 = gnx[tid]; gz2 = gnx[tid + H_]; gn2 = gnx[tid + 2 * H_];
        }

        // ---- phase A: partial dots over this thread's k-slice ----
        float p0 = 0.f, p1 = 0.f, p2 = 0.f;
        {
            float4 hv;
            hv = *(const float4*)&h2[hb];
            DOT4(p0, hv, w00) DOT4(p1, hv, w10) DOT4(p2, hv, w20)
            hv = *(const float4*)&h2[32 + hb];
            DOT4(p0, hv, w01) DOT4(p1, hv, w11) DOT4(p2, hv, w21)
            hv = *(const float4*)&h2[64 + hb];
            DOT4(p0, hv, w02) DOT4(p1, hv, w12) DOT4(p2, hv, w22)
            hv = *(const float4*)&h2[96 + hb];
            DOT4(p0, hv, w03) DOT4(p1, hv, w13) DOT4(p2, hv, w23)
        }

        p0 = bfly_fold8(p0);
        p1 = bfly_fold8(p1);
        p2 = bfly_fold8(p2);
        if (ks == 0) {
            gh[j0] = p0; gh[j0 + 1] = p1; gh[j0 + 2] = p2;
        }
        __syncthreads();

        // ---- phase B: gates on threads 0..127 ----
        if (gate) {
            const float ghr = gh[tid] + bhr;
            const float ghz = gh[tid + H_] + bhz;
            const float ghn = gh[tid + 2 * H_] + bhn;
            const float r = sigmoid_f(gr + ghr);
            const float z = sigmoid_f(gz + ghz);
            const float n = tanh_f(gn + r * ghn);
            h_old = (1.0f - z) * n + z * h_old;
            h2[hw] = h_old;
            if (STORE_H) hseq[((size_t)b * T_ + t) * H_ + tid] = h_old;
            gr = gr2; gz = gz2; gn = gn2;
        }
        __syncthreads();
    }

    if (FINAL) {
        if (gate) gh[tid] = fmaxf(h_old, 0.0f);   // relu(last hidden)
        __syncthreads();
        if (tid < 3) {
            float acc = fc_b[tid];
            const float* fw = fc_w + tid * H_;
#pragma unroll
            for (int k = 0; k < H_; k++) acc = fmaf(gh[k], fw[k], acc);
            out[b * 3 + tid] = acc;
        }
    }
}

// ---------------------------------------------------------------------------
extern "C" void kernel_launch(void* const* d_in, const int* in_sizes, int n_in,
                              void* d_out, int out_size, void* d_ws, size_t ws_size,
                              hipStream_t stream)
{
    const int*   x    = (const int*)  d_in[0];
    const float* emb  = (const float*)d_in[1];
    const float* W_ih = (const float*)d_in[2];  // [2,384,128]
    const float* W_hh = (const float*)d_in[3];  // [2,384,128]
    const float* b_ih = (const float*)d_in[4];  // [2,384]
    const float* b_hh = (const float*)d_in[5];  // [2,384]
    const float* fc_w = (const float*)d_in[6];  // [3,128]
    const float* fc_b = (const float*)d_in[7];  // [3]
    float* out = (float*)d_out;

    const int M = B_ * T_;                                   // 131072 rows
    const size_t gx_f32 = (size_t)M * G3_ * sizeof(float);   // 201.3 MB

    float* gx = (float*)d_ws;
    float* h1 = (float*)((char*)d_ws + gx_f32);              // 67.1 MB

    dim3 ggx(G3_ / TN, M / TM);   // (3, 1024)
    dim3 bgx(256);
    dim3 grec(B_), brec(1024);

    hipLaunchKernelGGL((gx_gemm<true>), ggx, bgx, 0, stream,
                       nullptr, x, emb, W_ih, b_ih, gx);
    hipLaunchKernelGGL((gru_rec<true, false>), grec, brec, REC_LDS_BYTES, stream,
                       gx, W_hh, b_hh, h1, nullptr, nullptr, nullptr);
    hipLaunchKernelGGL((gx_gemm<false>), ggx, bgx, 0, stream,
                       h1, nullptr, nullptr, W_ih + G3_ * H_, b_ih + G3_, gx);
    hipLaunchKernelGGL((gru_rec<false, true>), grec, brec, REC_LDS_BYTES, stream,
                       gx, W_hh + G3_ * H_, b_hh + G3_, nullptr, fc_w, fc_b, out);
}

// Round 2
// 982.502 us; speedup vs baseline: 1.1851x; 1.0611x over previous
//
#include <hip/hip_runtime.h>
#include <hip/hip_bf16.h>

#define B_   256
#define T_   512
#define H_   128
#define G3_  384

// ---- tiled GEMM config ----
#define TM   128
#define TN   128
#define TK   32
#define LDA  132

typedef float v4f __attribute__((ext_vector_type(4)));

__device__ __forceinline__ float sigmoid_f(float x) {
    return 1.0f / (1.0f + __expf(-x));
}
__device__ __forceinline__ float tanh_f(float x) {
    return 1.0f - 2.0f / (__expf(2.0f * x) + 1.0f);
}

// Butterfly sum over each aligned 4-lane quad, pure DPP, result on ALL lanes.
__device__ __forceinline__ float bfly_fold4(float v) {
    int x;
    x = __builtin_amdgcn_update_dpp(0, __float_as_int(v), 0x0B1, 0xF, 0xF, true);
    v += __int_as_float(x);   // xor 1
    x = __builtin_amdgcn_update_dpp(0, __float_as_int(v), 0x04E, 0xF, 0xF, true);
    v += __int_as_float(x);   // xor 2
    return v;
}

#define DOT4(acc, hv, wv)                                        \
    acc = fmaf((hv).x, (wv).x, acc);                             \
    acc = fmaf((hv).y, (wv).y, acc);                             \
    acc = fmaf((hv).z, (wv).z, acc);                             \
    acc = fmaf((hv).w, (wv).w, acc);

// ---------------------------------------------------------------------------
// gx GEMM (unchanged from R2 — ~140 us, healthy)
// ---------------------------------------------------------------------------
template<bool GATHER>
__global__ __launch_bounds__(256, 2)
void gx_gemm(const float* __restrict__ X,
             const int*   __restrict__ idx,
             const float* __restrict__ emb,
             const float* __restrict__ W,     // [384,128] row-major
             const float* __restrict__ bias,  // [384]
             float*       __restrict__ gx)    // [M,384]
{
    __shared__ __align__(16) float As[2][TK][LDA];
    __shared__ __align__(16) float Bs[2][TK][LDA];

    const int tid = threadIdx.x;
    const int tn  = tid & 15;
    const int tm  = tid >> 4;
    const int n0  = blockIdx.x * TN;
    const int m0  = blockIdx.y * TM;

    const int q  = tid & 7;
    const float* rowA[4];
    const float* rowB[4];
#pragma unroll
    for (int s = 0; s < 4; s++) {
        const int r = (tid >> 3) + 32 * s;
        rowA[s] = GATHER ? (emb + (size_t)idx[m0 + r] * H_)
                         : (X + (size_t)(m0 + r) * H_);
        rowB[s] = W + (size_t)(n0 + r) * H_;
    }

    float4 stA[4], stB[4];
    auto load_chunk = [&](int kc) {
#pragma unroll
        for (int s = 0; s < 4; s++) {
            stA[s] = *(const float4*)(rowA[s] + kc + q * 4);
            stB[s] = *(const float4*)(rowB[s] + kc + q * 4);
        }
    };
    auto store_chunk = [&](int buf) {
#pragma unroll
        for (int s = 0; s < 4; s++) {
            const int r = (tid >> 3) + 32 * s;
#pragma unroll
            for (int d = 0; d < 4; d++) {
                As[buf][q * 4 + d][r] = ((const float*)&stA[s])[d];
                Bs[buf][q * 4 + d][r] = ((const float*)&stB[s])[d];
            }
        }
    };

    float4 acc[2][2][4];
#pragma unroll
    for (int a = 0; a < 2; a++)
#pragma unroll
        for (int b = 0; b < 2; b++)
#pragma unroll
            for (int c = 0; c < 4; c++) acc[a][b][c] = make_float4(0.f, 0.f, 0.f, 0.f);

    load_chunk(0);
    store_chunk(0);
    __syncthreads();

    for (int c = 0; c < 4; c++) {
        if (c < 3) load_chunk((c + 1) * TK);
        const int buf = c & 1;
#pragma unroll 4
        for (int k = 0; k < TK; k++) {
            float4 a0 = *(const float4*)&As[buf][k][tm * 4];
            float4 a1 = *(const float4*)&As[buf][k][64 + tm * 4];
            float4 b0 = *(const float4*)&Bs[buf][k][tn * 4];
            float4 b1 = *(const float4*)&Bs[buf][k][64 + tn * 4];
            float4 av[2] = {a0, a1}, bv[2] = {b0, b1};
#pragma unroll
            for (int mg = 0; mg < 2; mg++)
#pragma unroll
                for (int mi = 0; mi < 4; mi++) {
                    const float am = ((const float*)&av[mg])[mi];
#pragma unroll
                    for (int ng = 0; ng < 2; ng++) {
                        acc[mg][ng][mi].x = fmaf(am, bv[ng].x, acc[mg][ng][mi].x);
                        acc[mg][ng][mi].y = fmaf(am, bv[ng].y, acc[mg][ng][mi].y);
                        acc[mg][ng][mi].z = fmaf(am, bv[ng].z, acc[mg][ng][mi].z);
                        acc[mg][ng][mi].w = fmaf(am, bv[ng].w, acc[mg][ng][mi].w);
                    }
                }
        }
        if (c < 3) {
            store_chunk(buf ^ 1);
            __syncthreads();
        }
    }

    const float4 bb0 = *(const float4*)(bias + n0 + tn * 4);
    const float4 bb1 = *(const float4*)(bias + n0 + 64 + tn * 4);
#pragma unroll
    for (int mg = 0; mg < 2; mg++)
#pragma unroll
        for (int mi = 0; mi < 4; mi++) {
            const int m = m0 + mg * 64 + tm * 4 + mi;
            float* dst = gx + (size_t)m * G3_ + n0;
            float4 v0 = acc[mg][0][mi];
            v0.x += bb0.x; v0.y += bb0.y; v0.z += bb0.z; v0.w += bb0.w;
            float4 v1 = acc[mg][1][mi];
            v1.x += bb1.x; v1.y += bb1.y; v1.z += bb1.z; v1.w += bb1.w;
            *(float4*)(dst + tn * 4) = v0;
            *(float4*)(dst + 64 + tn * 4) = v1;
        }
}

// ---------------------------------------------------------------------------
// GRU recurrence — R10 gate-ownership restructure.
//
// 512 threads/block, one block per batch row. Thread (jg = tid>>2, ks = tid&3)
// owns HIDDEN UNIT jg: W_hh rows jg (r), jg+128 (z), jg+256 (n), cols
// ks*32..+31 (96 floats in VGPRs; launch_bounds(512,2) -> 256-VGPR budget).
//
// After the 4-lane DPP fold, ALL lanes of group jg hold the full r/z/n dot
// products for unit jg -> the gate nonlinearity is computed redundantly
// in-register on all 4 lanes. This removes the old serial "phase B" (gates
// on 2 of 16 waves between two barriers, ~300-400 cyc/step of dead time),
// the gh[384] LDS round-trip, and — with a double-buffered h2 — one of the
// two per-step barriers.
//
// h2 swizzle: h[j] stored at word sw(j) = 16*((j>>2)&7) + 4*(j>>5) + (j&3).
// Read (group jg, slice ks, chunk c): float4 at word 16c + 4ks covers
// h[32ks+4c .. +3]; the 4 distinct ks addresses hit 4 distinct bank quads,
// the 16 redundant groups broadcast. Writes (ks==0, one word per unit) are
// <=2-way aliased (free).
// ---------------------------------------------------------------------------
template<bool STORE_H, bool FINAL>
__global__ __launch_bounds__(512, 2)
void gru_rec(const float* __restrict__ gx,   // [B,T,384]
             const float* __restrict__ Whh,  // [384,128]
             const float* __restrict__ bhh,  // [384]
             float*       __restrict__ hseq, // [B,T,128] if STORE_H
             const float* __restrict__ fc_w, // [3,128]  if FINAL
             const float* __restrict__ fc_b, // [3]      if FINAL
             float*       __restrict__ out)  // [B,3]    if FINAL
{
    __shared__ __align__(16) float h2[2][H_];   // double-buffered swizzled h

    const int tid = threadIdx.x;
    const int b   = blockIdx.x;
    const int jg  = tid >> 2;      // hidden unit 0..127
    const int ks  = tid & 3;       // k-slice 0..3 (32 cols each)

    // --- W_hh fragment: rows jg / jg+128 / jg+256, cols ks*32..+31 ---
    const v4f* wr = (const v4f*)(Whh + (size_t)(jg      ) * H_ + ks * 32);
    const v4f* wz = (const v4f*)(Whh + (size_t)(jg + 128) * H_ + ks * 32);
    const v4f* wn = (const v4f*)(Whh + (size_t)(jg + 256) * H_ + ks * 32);
    v4f Wr[8], Wz[8], Wn[8];
#pragma unroll
    for (int c = 0; c < 8; c++) { Wr[c] = wr[c]; Wz[c] = wz[c]; Wn[c] = wn[c]; }

    const float bhr = bhh[jg];
    const float bhz = bhh[jg + 128];
    const float bhn = bhh[jg + 256];

    const float* gxb = gx + (size_t)b * T_ * G3_;
    float gr = gxb[jg], gz = gxb[jg + 128], gn = gxb[jg + 256];
    float h_old = 0.0f;

    if (tid < H_) h2[0][tid] = 0.0f;   // zeros are swizzle-invariant

    // write word for this unit: sw(jg)
    const int hw = ((jg >> 2) & 7) * 16 + (jg >> 5) * 4 + (jg & 3);
    const int hb = ks * 4;             // read base within each 16-word chunk

    __syncthreads();

    // keep the W fragment register-resident (cannot be re-sunk into the loop)
#pragma unroll
    for (int c = 0; c < 8; c++) {
        asm volatile("" : "+v"(Wr[c]), "+v"(Wz[c]), "+v"(Wn[c]));
    }

#define GRU_STEP(HIN, HOUT, TT)                                               \
    {                                                                         \
        const int tn_ = ((TT) + 1 < T_) ? (TT) + 1 : T_ - 1;                  \
        const float* gnx_ = gxb + (size_t)tn_ * G3_;                          \
        const float gr2_ = gnx_[jg];                                          \
        const float gz2_ = gnx_[jg + 128];                                    \
        const float gn2_ = gnx_[jg + 256];                                    \
        float p0 = 0.f, p1 = 0.f, p2 = 0.f;                                   \
        _Pragma("unroll")                                                     \
        for (int c = 0; c < 8; c++) {                                         \
            float4 hv = *(const float4*)&(HIN)[16 * c + hb];                  \
            DOT4(p0, hv, Wr[c]) DOT4(p1, hv, Wz[c]) DOT4(p2, hv, Wn[c])      \
        }                                                                     \
        p0 = bfly_fold4(p0);                                                  \
        p1 = bfly_fold4(p1);                                                  \
        p2 = bfly_fold4(p2);                                                  \
        const float r_ = sigmoid_f(gr + p0 + bhr);                            \
        const float z_ = sigmoid_f(gz + p1 + bhz);                            \
        const float n_ = tanh_f(gn + r_ * (p2 + bhn));                        \
        h_old = (1.0f - z_) * n_ + z_ * h_old;                                \
        if (ks == 0) {                                                        \
            (HOUT)[hw] = h_old;                                               \
            if (STORE_H) hseq[((size_t)b * T_ + (TT)) * H_ + jg] = h_old;     \
        }                                                                     \
        gr = gr2_; gz = gz2_; gn = gn2_;                                      \
        __syncthreads();                                                      \
    }

    for (int t = 0; t < T_; t += 2) {
        GRU_STEP(h2[0], h2[1], t)
        GRU_STEP(h2[1], h2[0], t + 1)
    }
#undef GRU_STEP

    if (FINAL) {
        // h2[1] is dead after the loop's trailing barrier — reuse linearly.
        if (ks == 0) h2[1][jg] = fmaxf(h_old, 0.0f);   // relu(last hidden)
        __syncthreads();
        if (tid < 3) {
            float acc = fc_b[tid];
            const float* fw = fc_w + tid * H_;
#pragma unroll
            for (int k = 0; k < H_; k++) acc = fmaf(h2[1][k], fw[k], acc);
            out[b * 3 + tid] = acc;
        }
    }
}

// ---------------------------------------------------------------------------
extern "C" void kernel_launch(void* const* d_in, const int* in_sizes, int n_in,
                              void* d_out, int out_size, void* d_ws, size_t ws_size,
                              hipStream_t stream)
{
    const int*   x    = (const int*)  d_in[0];
    const float* emb  = (const float*)d_in[1];
    const float* W_ih = (const float*)d_in[2];  // [2,384,128]
    const float* W_hh = (const float*)d_in[3];  // [2,384,128]
    const float* b_ih = (const float*)d_in[4];  // [2,384]
    const float* b_hh = (const float*)d_in[5];  // [2,384]
    const float* fc_w = (const float*)d_in[6];  // [3,128]
    const float* fc_b = (const float*)d_in[7];  // [3]
    float* out = (float*)d_out;

    const int M = B_ * T_;                                   // 131072 rows
    const size_t gx_f32 = (size_t)M * G3_ * sizeof(float);   // 201.3 MB

    float* gx = (float*)d_ws;
    float* h1 = (float*)((char*)d_ws + gx_f32);              // 67.1 MB

    dim3 ggx(G3_ / TN, M / TM);   // (3, 1024)
    dim3 bgx(256);
    dim3 grec(B_), brec(512);

    hipLaunchKernelGGL((gx_gemm<true>), ggx, bgx, 0, stream,
                       nullptr, x, emb, W_ih, b_ih, gx);
    hipLaunchKernelGGL((gru_rec<true, false>), grec, brec, 0, stream,
                       gx, W_hh, b_hh, h1, nullptr, nullptr, nullptr);
    hipLaunchKernelGGL((gx_gemm<false>), ggx, bgx, 0, stream,
                       h1, nullptr, nullptr, W_ih + G3_ * H_, b_ih + G3_, gx);
    hipLaunchKernelGGL((gru_rec<false, true>), grec, brec, 0, stream,
                       gx, W_hh + G3_ * H_, b_hh + G3_, nullptr, fc_w, fc_b, out);
}